// Round 5
// baseline (1510.569 us; speedup 1.0000x reference)
//
#include <hip/hip_runtime.h>
#include <hip/hip_bf16.h>
#include <cmath>

#define BB 2
#define SS 2048
#define DD 2048
#define HHN 16
#define DHH 128
#define FFF 8192
#define NFF (3*DD+FFF)   // 14336
#define MR (BB*SS)       // 4096
#define LNEPS 1e-6f

typedef __hip_bfloat16 bf16;
using bf16x8 = __attribute__((ext_vector_type(8))) __bf16;
using f32x4  = __attribute__((ext_vector_type(4))) float;
using f32x16 = __attribute__((ext_vector_type(16))) float;

// async global->LDS copy, 16B per lane. HW semantics: LDS dest = wave-uniform
// base + lane*16. Every call site below satisfies: lds_byte_off = uniform + lane*16.
__device__ __forceinline__ void async_copy16(const bf16* g, bf16* l) {
  __builtin_amdgcn_global_load_lds(
      (const __attribute__((address_space(1))) void*)g,
      (__attribute__((address_space(3))) void*)l, 16, 0, 0);
}

// ---------------- convert f32 -> bf16 (vectorized) ----------------
__global__ __launch_bounds__(256) void k_convert(const float* __restrict__ in,
                                                 bf16* __restrict__ out, int n4) {
  int i = blockIdx.x * 256 + threadIdx.x;
  if (i >= n4) return;
  float4 v = ((const float4*)in)[i];
  out[4*i+0] = __float2bfloat16(v.x);
  out[4*i+1] = __float2bfloat16(v.y);
  out[4*i+2] = __float2bfloat16(v.z);
  out[4*i+3] = __float2bfloat16(v.w);
}

// ---------------- transpose+convert: in (R x C) f32 -> out (C x R) bf16 ----------------
__global__ __launch_bounds__(256) void k_transpose(const float* __restrict__ in,
                                                   bf16* __restrict__ out, int R, int C) {
  __shared__ float tile[32][33];
  int c0 = blockIdx.x * 32, r0 = blockIdx.y * 32;
  int tx = threadIdx.x, ty = threadIdx.y;
  #pragma unroll
  for (int i = 0; i < 32; i += 8)
    tile[ty + i][tx] = in[(size_t)(r0 + ty + i) * C + (c0 + tx)];
  __syncthreads();
  #pragma unroll
  for (int i = 0; i < 32; i += 8)
    out[(size_t)(c0 + ty + i) * R + (r0 + tx)] = __float2bfloat16(tile[tx][ty + i]);
}

// ---------------- V pre-transpose: fused v-region -> vT[bh][d][s] (bf16) ----------------
__global__ void k_vtrans(const bf16* __restrict__ fused, bf16* __restrict__ vT) {
  __shared__ bf16 tile[32][33];
  int s0 = blockIdx.x * 32, d0 = blockIdx.y * 32, bh = blockIdx.z;
  int b = bh >> 4, h = bh & 15;
  int tx = threadIdx.x, ty = threadIdx.y;
  const bf16* src = fused + (size_t)(b * SS) * NFF + 2 * DD + h * DHH;
  #pragma unroll
  for (int i = 0; i < 32; i += 8)
    tile[ty + i][tx] = src[(size_t)(s0 + ty + i) * NFF + d0 + tx];
  __syncthreads();
  bf16* dst = vT + ((size_t)bh * DHH) * SS;
  #pragma unroll
  for (int i = 0; i < 32; i += 8)
    dst[(size_t)(d0 + ty + i) * SS + s0 + tx] = tile[tx][ty + i];
}

// ---------------- bf16 MFMA GEMM, 128x128 tile, 32x32x16 MFMA, BK=64 ----------------
// C[MxN] = A[MxK] @ BT[NxK]^T + bias
// mode 0/1: C bf16 = v ; mode 2: C bf16 = addin(bf16) + silu(v)
// 4 waves 2x2; wave owns 64x64 = 2x2 MFMA-32 blocks.
// LDS chunked [c:8][row:128][8 bf16] (c = k_local/8): async-compatible
// (uniform+lane*16) AND conflict-free b128 fragment reads (contiguous granules).
// 32x32x16 layouts: A/B lane l holds [m|n = l&31][k = (l>>5)*8 + j];
// C/D: col = l&31, row = (r&3) + 8*(r>>2) + 4*(l>>5), r in [0,16)  [m74/m101]
__global__ __launch_bounds__(256) void k_gemm_bt(const bf16* __restrict__ A,
                                                 const bf16* __restrict__ BT,
                                                 const float* __restrict__ bias,
                                                 bf16* __restrict__ Cout,
                                                 const bf16* __restrict__ addin,
                                                 int M, int N, int K, int mode) {
  __shared__ __align__(16) bf16 As[8192];  // 16 KiB
  __shared__ __align__(16) bf16 Bs[8192];  // 16 KiB
  int NBm = M >> 7;
  constexpr int PW = 16;
  int bid = blockIdx.x;
  int pid = bid / (PW * NBm), rem = bid % (PW * NBm);
  int by = rem / PW, bx = pid * PW + rem % PW;
  int tid = threadIdx.x;
  int w = tid >> 6, l = tid & 63;
  int wm = w >> 1, wn = w & 1;
  int l31 = l & 31, kg = l >> 5;
  int m0 = by * 128, n0 = bx * 128;

  f32x16 acc[2][2];
  #pragma unroll
  for (int i = 0; i < 2; i++)
    #pragma unroll
    for (int j = 0; j < 2; j++)
      #pragma unroll
      for (int r = 0; r < 16; r++) acc[i][j][r] = 0.f;

  for (int k0 = 0; k0 < K; k0 += 64) {
    __syncthreads();  // previous stage's readers done
    #pragma unroll
    for (int j = 0; j < 4; j++) {
      int i = j * 4 + w;                  // 0..15 wave-calls
      int c = i >> 1, mm = (i & 1) * 64 + l;
      async_copy16(A + (size_t)(m0 + mm) * K + k0 + c * 8, &As[(c * 128 + mm) * 8]);
      async_copy16(BT + (size_t)(n0 + mm) * K + k0 + c * 8, &Bs[(c * 128 + mm) * 8]);
    }
    __syncthreads();  // drains vmcnt

    #pragma unroll
    for (int t = 0; t < 4; t++) {        // k-steps of 16
      bf16x8 af[2], bf_[2];
      #pragma unroll
      for (int mi = 0; mi < 2; mi++)
        af[mi] = *reinterpret_cast<const bf16x8*>(
            &As[((t * 2 + kg) * 128 + wm * 64 + mi * 32 + l31) * 8]);
      #pragma unroll
      for (int nj = 0; nj < 2; nj++)
        bf_[nj] = *reinterpret_cast<const bf16x8*>(
            &Bs[((t * 2 + kg) * 128 + wn * 64 + nj * 32 + l31) * 8]);
      #pragma unroll
      for (int mi = 0; mi < 2; mi++)
        #pragma unroll
        for (int nj = 0; nj < 2; nj++)
          acc[mi][nj] = __builtin_amdgcn_mfma_f32_32x32x16_bf16(
              af[mi], bf_[nj], acc[mi][nj], 0, 0, 0);
    }
  }

  #pragma unroll
  for (int mi = 0; mi < 2; mi++) {
    #pragma unroll
    for (int nj = 0; nj < 2; nj++) {
      int col = n0 + wn * 64 + nj * 32 + l31;
      int rbase = m0 + wm * 64 + mi * 32 + 4 * kg;
      float bv = bias[col];
      #pragma unroll
      for (int r = 0; r < 16; r++) {
        int row = rbase + (r & 3) + 8 * (r >> 2);
        size_t idx = (size_t)row * N + col;
        float v = acc[mi][nj][r] + bv;
        if (mode == 2) {
          float sig = 1.f / (1.f + expf(-v));
          v = __bfloat162float(addin[idx]) + v * sig;
        }
        Cout[idx] = __float2bfloat16(v);
      }
    }
  }
}

// ---------------- cos/sin table: tab[s*DHH+d] = {cos(rw), sin(rw)} ----------------
__global__ __launch_bounds__(256) void k_sincos(const float* __restrict__ rope_w,
                                                float2* __restrict__ tab) {
  int i = blockIdx.x * 256 + threadIdx.x;
  if (i >= SS * DHH) return;
  float v = rope_w[i];
  tab[i] = make_float2(cosf(v), sinf(v));
}

// ---------------- RoPE in-place on q,k of fused (vectorized, table-driven) ----------------
// ref rotate_half has NO negation: out[d]=x[d]*c[d]+x[d+64]*s[d]; out[d+64]=x[d+64]*c[d+64]+x[d]*s[d+64]
__global__ __launch_bounds__(256) void k_rope(bf16* __restrict__ fused,
                                              const float2* __restrict__ tab) {
  int row = blockIdx.x;
  int s = row & (SS - 1);
  const float2* tr = tab + (size_t)s * DHH;
  int tid = threadIdx.x;
  int isK = tid >> 7, ch = tid & 127;
  int h = ch >> 3, c0 = (ch & 7) * 8;
  const float scale = 0.08838834764831845f;  // 1/sqrt(128); q only
  bf16* base = fused + (size_t)row * NFF + isK * DD + h * DHH;
  bf16x8 lo = *reinterpret_cast<const bf16x8*>(base + c0);
  bf16x8 hi = *reinterpret_cast<const bf16x8*>(base + c0 + 64);
  bf16x8 olo, ohi;
  #pragma unroll
  for (int t = 0; t < 8; t++) {
    int d = c0 + t;
    float2 cl = tr[d], chh = tr[d + 64];
    float x0 = (float)lo[t], x1 = (float)hi[t];
    float r0 = x0 * cl.x + x1 * cl.y;
    float r1 = x1 * chh.x + x0 * chh.y;
    if (!isK) { r0 *= scale; r1 *= scale; }
    olo[t] = (__bf16)r0;
    ohi[t] = (__bf16)r1;
  }
  *reinterpret_cast<bf16x8*>(base + c0) = olo;
  *reinterpret_cast<bf16x8*>(base + c0 + 64) = ohi;
}

// ---------------- causal flash attention, MFMA + async staging ----------------
// grid: (S/64, B*H), 256 threads = 4 waves. Wave w owns q-rows [w*16, w*16+16).
// LDS layouts all [chunk][row][32] unpadded (m97 pattern; async-compatible).
__global__ __launch_bounds__(256) void k_flash(const bf16* __restrict__ fused,
                                               const bf16* __restrict__ vT,
                                               bf16* __restrict__ obuf) {
  __shared__ __align__(16) bf16 smem[20480];  // 40 KiB
  bf16* Ks = smem;          // [4][64][32]  16 KiB  (chunk=ks over d)
  bf16* Vt = smem + 8192;   // [2][128][32] 16 KiB  (chunk=kc over keys, row=d)
  bf16* Ps = smem + 16384;  // [2][64][32]   8 KiB  (chunk over keys, wave-private rows)
  bf16* Qs = smem;          // overlay with Ks (Q frags hoisted before loop)

  int qb = blockIdx.x, bh = blockIdx.y;
  int b = bh >> 4, h = bh & 15;
  int tid = threadIdx.x;
  int w = tid >> 6, l = tid & 63;
  int l15 = l & 15, g = l >> 4;

  const bf16* qbase = fused + (size_t)(b * SS + qb * 64) * NFF + h * DHH;
  const bf16* kbase = fused + (size_t)(b * SS) * NFF + DD + h * DHH;
  const bf16* vtb = vT + (size_t)bh * DHH * SS;

  // ---- stage Q (64 rows x 128 d) async ----
  #pragma unroll
  for (int ks = 0; ks < 4; ks++)
    async_copy16(qbase + (size_t)(w * 16 + (l >> 2)) * NFF + ks * 32 + (l & 3) * 8,
                 &Qs[ks * 2048 + w * 512 + l * 8]);
  __syncthreads();
  bf16x8 qf[4];
  #pragma unroll
  for (int ks = 0; ks < 4; ks++)
    qf[ks] = *reinterpret_cast<const bf16x8*>(&Qs[ks * 2048 + (w * 16 + l15) * 32 + g * 8]);

  f32x4 o[8];
  #pragma unroll
  for (int nt = 0; nt < 8; nt++) o[nt] = f32x4{0.f, 0.f, 0.f, 0.f};
  float m_i[4], l_i[4];
  #pragma unroll
  for (int r = 0; r < 4; r++) { m_i[r] = -1e30f; l_i[r] = 0.f; }
  int qrow_base = qb * 64 + w * 16 + g * 4;  // + r

  for (int kt = 0; kt <= qb; kt++) {
    __syncthreads();  // all waves done reading Qs/Ks/Vt
    #pragma unroll
    for (int ks = 0; ks < 4; ks++)
      async_copy16(kbase + (size_t)(kt * 64 + w * 16 + (l >> 2)) * NFF + ks * 32 + (l & 3) * 8,
                   &Ks[ks * 2048 + w * 512 + l * 8]);
    #pragma unroll
    for (int j = 0; j < 2; j++)
      #pragma unroll
      for (int kc = 0; kc < 2; kc++)
        async_copy16(vtb + (size_t)(j * 64 + w * 16 + (l >> 2)) * SS + kt * 64 + kc * 32 + (l & 3) * 8,
                     &Vt[kc * 4096 + j * 2048 + w * 512 + l * 8]);
    __syncthreads();  // drains vmcnt

    f32x4 s[4];
    #pragma unroll
    for (int nt = 0; nt < 4; nt++) {
      s[nt] = f32x4{0.f, 0.f, 0.f, 0.f};
      #pragma unroll
      for (int ks = 0; ks < 4; ks++) {
        bf16x8 bfrag = *reinterpret_cast<const bf16x8*>(
            &Ks[ks * 2048 + (nt * 16 + l15) * 32 + g * 8]);
        s[nt] = __builtin_amdgcn_mfma_f32_16x16x32_bf16(qf[ks], bfrag, s[nt], 0, 0, 0);
      }
    }
    #pragma unroll
    for (int nt = 0; nt < 4; nt++) {
      int kk = kt * 64 + nt * 16 + l15;
      #pragma unroll
      for (int r = 0; r < 4; r++)
        if (kk > qrow_base + r) s[nt][r] = -1e30f;
    }
    float alpha[4];
    #pragma unroll
    for (int r = 0; r < 4; r++) {
      float mx = fmaxf(fmaxf(s[0][r], s[1][r]), fmaxf(s[2][r], s[3][r]));
      mx = fmaxf(mx, __shfl_xor(mx, 1));
      mx = fmaxf(mx, __shfl_xor(mx, 2));
      mx = fmaxf(mx, __shfl_xor(mx, 4));
      mx = fmaxf(mx, __shfl_xor(mx, 8));
      float mnew = fmaxf(m_i[r], mx);
      alpha[r] = __expf(m_i[r] - mnew);
      m_i[r] = mnew;
      float ls = 0.f;
      #pragma unroll
      for (int nt = 0; nt < 4; nt++) {
        float p = __expf(s[nt][r] - mnew);
        s[nt][r] = p;
        ls += p;
      }
      ls += __shfl_xor(ls, 1);
      ls += __shfl_xor(ls, 2);
      ls += __shfl_xor(ls, 4);
      ls += __shfl_xor(ls, 8);
      l_i[r] = l_i[r] * alpha[r] + ls;
    }
    #pragma unroll
    for (int nt = 0; nt < 4; nt++) {
      int kk = nt * 16 + l15;
      #pragma unroll
      for (int r = 0; r < 4; r++)
        *(__bf16*)&Ps[(kk >> 5) * 2048 + (w * 16 + g * 4 + r) * 32 + (kk & 31)] =
            (__bf16)s[nt][r];
    }
    #pragma unroll
    for (int nt = 0; nt < 8; nt++)
      #pragma unroll
      for (int r = 0; r < 4; r++) o[nt][r] *= alpha[r];
    bf16x8 pf[2];
    #pragma unroll
    for (int ks = 0; ks < 2; ks++)
      pf[ks] = *reinterpret_cast<const bf16x8*>(
          &Ps[ks * 2048 + (w * 16 + l15) * 32 + g * 8]);
    #pragma unroll
    for (int nt = 0; nt < 8; nt++)
      #pragma unroll
      for (int ks = 0; ks < 2; ks++) {
        bf16x8 bfrag = *reinterpret_cast<const bf16x8*>(
            &Vt[ks * 4096 + (nt * 16 + l15) * 32 + g * 8]);
        o[nt] = __builtin_amdgcn_mfma_f32_16x16x32_bf16(pf[ks], bfrag, o[nt], 0, 0, 0);
      }
  }

  float inv[4];
  #pragma unroll
  for (int r = 0; r < 4; r++) inv[r] = 1.f / l_i[r];
  #pragma unroll
  for (int nt = 0; nt < 8; nt++)
    #pragma unroll
    for (int r = 0; r < 4; r++) {
      size_t row = (size_t)(b * SS + qrow_base + r);
      obuf[row * DD + h * DHH + nt * 16 + l15] = __float2bfloat16(o[nt][r] * inv[r]);
    }
}

// ---------------- LayerNorm(ff) + ReLU -> h (bf16), single-pass, vectorized ----------------
__global__ __launch_bounds__(256) void k_ln1_relu(const bf16* __restrict__ fused,
                                                  const float* __restrict__ gamma,
                                                  const float* __restrict__ beta,
                                                  bf16* __restrict__ h) {
  int row = blockIdx.x;
  const bf16* xr = fused + (size_t)row * NFF + 3 * DD;
  int tid = threadIdx.x;
  bf16x8 v8[4];
  float s = 0.f, ss = 0.f;
  #pragma unroll
  for (int k = 0; k < 4; k++) {
    v8[k] = *reinterpret_cast<const bf16x8*>(xr + (tid + k * 256) * 8);
    #pragma unroll
    for (int t = 0; t < 8; t++) {
      float v = (float)v8[k][t];
      s += v; ss += v * v;
    }
  }
  #pragma unroll
  for (int off = 32; off > 0; off >>= 1) { s += __shfl_down(s, off); ss += __shfl_down(ss, off); }
  __shared__ float red[8];
  int wave = tid >> 6, lane = tid & 63;
  if (lane == 0) { red[wave] = s; red[4 + wave] = ss; }
  __syncthreads();
  if (tid == 0) {
    float S0 = red[0] + red[1] + red[2] + red[3];
    float SQ = red[4] + red[5] + red[6] + red[7];
    float m = S0 / FFF;
    float var = SQ / FFF - m * m;
    red[0] = m;
    red[1] = 1.f / sqrtf(var + LNEPS);
  }
  __syncthreads();
  float m = red[0], inv = red[1];
  bf16* hr = h + (size_t)row * FFF;
  #pragma unroll
  for (int k = 0; k < 4; k++) {
    bf16x8 o8;
    int base = (tid + k * 256) * 8;
    #pragma unroll
    for (int t = 0; t < 8; t++) {
      float v = (float)v8[k][t];
      float y = gamma[base + t] * (v - m) * inv + beta[base + t];
      o8[t] = (__bf16)fmaxf(y, 0.f);
    }
    *reinterpret_cast<bf16x8*>(hr + base) = o8;
  }
}

// ---------------- final LayerNorm (bf16 in -> f32 out), single-pass, vectorized ----------------
__global__ __launch_bounds__(256) void k_ln2(const bf16* __restrict__ yin,
                                             const float* __restrict__ gamma,
                                             const float* __restrict__ beta,
                                             float* __restrict__ out) {
  int row = blockIdx.x;
  const bf16* xr = yin + (size_t)row * DD;
  int tid = threadIdx.x;
  bf16x8 v8 = *reinterpret_cast<const bf16x8*>(xr + tid * 8);
  float s = 0.f, ss = 0.f;
  #pragma unroll
  for (int t = 0; t < 8; t++) {
    float v = (float)v8[t];
    s += v; ss += v * v;
  }
  #pragma unroll
  for (int off = 32; off > 0; off >>= 1) { s += __shfl_down(s, off); ss += __shfl_down(ss, off); }
  __shared__ float red[8];
  int wave = tid >> 6, lane = tid & 63;
  if (lane == 0) { red[wave] = s; red[4 + wave] = ss; }
  __syncthreads();
  if (tid == 0) {
    float S0 = red[0] + red[1] + red[2] + red[3];
    float SQ = red[4] + red[5] + red[6] + red[7];
    float m = S0 / DD;
    float var = SQ / DD - m * m;
    red[0] = m;
    red[1] = 1.f / sqrtf(var + LNEPS);
  }
  __syncthreads();
  float m = red[0], inv = red[1];
  float4* orow = (float4*)(out + (size_t)row * DD);
  #pragma unroll
  for (int k = 0; k < 2; k++) {
    int base = tid * 8 + k * 4;
    float4 r;
    r.x = gamma[base + 0] * ((float)v8[k * 4 + 0] - m) * inv + beta[base + 0];
    r.y = gamma[base + 1] * ((float)v8[k * 4 + 1] - m) * inv + beta[base + 1];
    r.z = gamma[base + 2] * ((float)v8[k * 4 + 2] - m) * inv + beta[base + 2];
    r.w = gamma[base + 3] * ((float)v8[k * 4 + 3] - m) * inv + beta[base + 3];
    orow[tid * 2 + k] = r;
  }
}

extern "C" void kernel_launch(void* const* d_in, const int* in_sizes, int n_in,
                              void* d_out, int out_size, void* d_ws, size_t ws_size,
                              hipStream_t stream) {
  const float* x       = (const float*)d_in[0];
  const float* W_fused = (const float*)d_in[1];
  const float* b_fused = (const float*)d_in[2];
  const float* W_attn  = (const float*)d_in[3];
  const float* b_attn  = (const float*)d_in[4];
  const float* W_ff    = (const float*)d_in[5];
  const float* b_ff    = (const float*)d_in[6];
  const float* gamma1  = (const float*)d_in[7];
  const float* beta1   = (const float*)d_in[8];
  const float* gamma2  = (const float*)d_in[9];
  const float* beta2   = (const float*)d_in[10];
  const float* rope_w  = (const float*)d_in[11];

  char* ws = (char*)d_ws;
  size_t off = 0;
  auto alloc = [&](size_t bytes) -> void* {
    void* p = ws + off;
    off += (bytes + 255) & ~(size_t)255;
    return p;
  };
  bf16* fused = (bf16*)alloc((size_t)MR * NFF * 2);   // 112 MiB
  bf16* xb    = (bf16*)alloc((size_t)MR * DD * 2);    // 16 MiB (dead after fused GEMM)
  bf16* WfT   = (bf16*)alloc((size_t)NFF * DD * 2);   // 56 MiB
  bf16* WaT   = (bf16*)alloc((size_t)DD * DD * 2);    // 8 MiB
  bf16* WffT  = (bf16*)alloc((size_t)DD * FFF * 2);   // 32 MiB
  bf16* hbuf  = (bf16*)alloc((size_t)MR * FFF * 2);   // 64 MiB
  bf16* obuf  = (bf16*)alloc((size_t)MR * DD * 2);    // 16 MiB
  bf16* ybuf  = (bf16*)alloc((size_t)MR * DD * 2);    // 16 MiB (bf16 now)
  float* tabf = (float*)alloc((size_t)SS * DHH * 8);  // 2 MiB cos/sin table
  if (off > ws_size) return;
  bf16* vT = xb;               // overlay: V^T [bh][d][s], live vtrans..flash
  float2* tab = (float2*)tabf;

  // 1. convert x -> bf16 ; cos/sin table
  k_convert<<<(MR * DD / 4 + 255) / 256, 256, 0, stream>>>(x, xb, MR * DD / 4);
  k_sincos<<<(SS * DHH + 255) / 256, 256, 0, stream>>>(rope_w, tab);
  // 2. transpose weights -> bf16 B^T
  k_transpose<<<dim3(NFF / 32, DD / 32), dim3(32, 8), 0, stream>>>(W_fused, WfT, DD, NFF);
  k_transpose<<<dim3(DD / 32, DD / 32), dim3(32, 8), 0, stream>>>(W_attn, WaT, DD, DD);
  k_transpose<<<dim3(DD / 32, FFF / 32), dim3(32, 8), 0, stream>>>(W_ff, WffT, FFF, DD);
  // 3. fused = x @ W_fused + b_fused   (bf16 out)
  k_gemm_bt<<<(NFF / 128) * (MR / 128), 256, 0, stream>>>(xb, WfT, b_fused, fused, nullptr,
                                                          MR, NFF, DD, 1);
  // 4. RoPE on q,k (table-driven, vectorized)
  k_rope<<<MR, 256, 0, stream>>>(fused, tab);
  // 5. V^T -> vT (xb now dead), then causal flash attention (MFMA, async staging)
  k_vtrans<<<dim3(SS / 32, DHH / 32, BB * HHN), dim3(32, 8), 0, stream>>>(fused, vT);
  k_flash<<<dim3(SS / 64, BB * HHN), 256, 0, stream>>>(fused, vT, obuf);
  // 6. attn = o @ W_attn + b_attn   (bf16 out -> ybuf)
  k_gemm_bt<<<(DD / 128) * (MR / 128), 256, 0, stream>>>(obuf, WaT, b_attn, ybuf, nullptr,
                                                         MR, DD, DD, 0);
  // 7. h = relu(layernorm(ff))   (bf16)
  k_ln1_relu<<<MR, 256, 0, stream>>>(fused, gamma1, beta1, hbuf);
  // 8. ybuf = attn + silu(h @ W_ff + b_ff)   (in-place add, bf16)
  k_gemm_bt<<<(DD / 128) * (MR / 128), 256, 0, stream>>>(hbuf, WffT, b_ff, ybuf, ybuf,
                                                         MR, DD, FFF, 2);
  // 9. out = layernorm(ybuf)
  k_ln2<<<MR, 256, 0, stream>>>(ybuf, gamma2, beta2, (float*)d_out);
}

// Round 6
// 1135.311 us; speedup vs baseline: 1.3305x; 1.3305x over previous
//
#include <hip/hip_runtime.h>
#include <hip/hip_bf16.h>
#include <cmath>

#define BB 2
#define SS 2048
#define DD 2048
#define HHN 16
#define DHH 128
#define FFF 8192
#define NFF (3*DD+FFF)   // 14336
#define MR (BB*SS)       // 4096
#define LNEPS 1e-6f

typedef __hip_bfloat16 bf16;
using bf16x8 = __attribute__((ext_vector_type(8))) __bf16;
using f32x4  = __attribute__((ext_vector_type(4))) float;

// async global->LDS copy, 16B per lane. HW semantics: LDS dest = wave-uniform
// base + lane*16. Every call site below satisfies: lds_byte_off = uniform + lane*16,
// AND global addrs are 64B-contiguous per 4 lanes (coalesced) — R5 lesson: never
// trade global coalescing for LDS-conflict-freedom on this path.
__device__ __forceinline__ void async_copy16(const bf16* g, bf16* l) {
  __builtin_amdgcn_global_load_lds(
      (const __attribute__((address_space(1))) void*)g,
      (__attribute__((address_space(3))) void*)l, 16, 0, 0);
}

// ---------------- convert f32 -> bf16 (vectorized) ----------------
__global__ __launch_bounds__(256) void k_convert(const float* __restrict__ in,
                                                 bf16* __restrict__ out, int n4) {
  int i = blockIdx.x * 256 + threadIdx.x;
  if (i >= n4) return;
  float4 v = ((const float4*)in)[i];
  out[4*i+0] = __float2bfloat16(v.x);
  out[4*i+1] = __float2bfloat16(v.y);
  out[4*i+2] = __float2bfloat16(v.z);
  out[4*i+3] = __float2bfloat16(v.w);
}

// ---------------- transpose+convert: in (R x C) f32 -> out (C x R) bf16 ----------------
__global__ __launch_bounds__(256) void k_transpose(const float* __restrict__ in,
                                                   bf16* __restrict__ out, int R, int C) {
  __shared__ float tile[32][33];
  int c0 = blockIdx.x * 32, r0 = blockIdx.y * 32;
  int tx = threadIdx.x, ty = threadIdx.y;
  #pragma unroll
  for (int i = 0; i < 32; i += 8)
    tile[ty + i][tx] = in[(size_t)(r0 + ty + i) * C + (c0 + tx)];
  __syncthreads();
  #pragma unroll
  for (int i = 0; i < 32; i += 8)
    out[(size_t)(c0 + ty + i) * R + (r0 + tx)] = __float2bfloat16(tile[tx][ty + i]);
}

// ---------------- V pre-transpose: fused v-region -> vT[bh][d][s] (bf16) ----------------
__global__ void k_vtrans(const bf16* __restrict__ fused, bf16* __restrict__ vT) {
  __shared__ bf16 tile[32][33];
  int s0 = blockIdx.x * 32, d0 = blockIdx.y * 32, bh = blockIdx.z;
  int b = bh >> 4, h = bh & 15;
  int tx = threadIdx.x, ty = threadIdx.y;
  const bf16* src = fused + (size_t)(b * SS) * NFF + 2 * DD + h * DHH;
  #pragma unroll
  for (int i = 0; i < 32; i += 8)
    tile[ty + i][tx] = src[(size_t)(s0 + ty + i) * NFF + d0 + tx];
  __syncthreads();
  bf16* dst = vT + ((size_t)bh * DHH) * SS;
  #pragma unroll
  for (int i = 0; i < 32; i += 8)
    dst[(size_t)(d0 + ty + i) * SS + s0 + tx] = tile[tx][ty + i];
}

// ---------------- bf16 MFMA GEMM, 128x128 tile (m97 structure, R4 config) -------------
// C[MxN] = A[MxK] @ BT[NxK]^T + bias ; bf16 output
// mode 0/1: C = v ; mode 2: C = addin + silu(v)
// LDS unpadded [128][32] row-major (global_load_lds contract); staging 4 lanes/row,
// 64B contiguous per row-segment (coalesced) — the measured 373us/636TF config.
__global__ __launch_bounds__(256) void k_gemm_bt(const bf16* __restrict__ A,
                                                 const bf16* __restrict__ BT,
                                                 const float* __restrict__ bias,
                                                 bf16* __restrict__ Cout,
                                                 const bf16* __restrict__ addin,
                                                 int M, int N, int K, int mode) {
  __shared__ __align__(16) bf16 As[128 * 32];  // 8 KiB
  __shared__ __align__(16) bf16 Bs[128 * 32];  // 8 KiB
  int NBm = M >> 7;
  constexpr int PW = 16;
  int bid = blockIdx.x;
  int pid = bid / (PW * NBm), rem = bid % (PW * NBm);
  int by = rem / PW, bx = pid * PW + rem % PW;
  int tid = threadIdx.x;
  int w = tid >> 6, l = tid & 63;
  int wm = w >> 1, wn = w & 1;
  int l15 = l & 15, g = l >> 4;
  int sr4 = l >> 2, sc4 = (l & 3) * 8;
  int m0 = by * 128, n0 = bx * 128;

  f32x4 acc[4][4];
  #pragma unroll
  for (int i = 0; i < 4; i++)
    #pragma unroll
    for (int j = 0; j < 4; j++)
      acc[i][j] = f32x4{0.f, 0.f, 0.f, 0.f};

  for (int k0 = 0; k0 < K; k0 += 32) {
    __syncthreads();
    #pragma unroll
    for (int i = 0; i < 2; i++) {
      int r = (w * 2 + i) * 16 + sr4;  // 0..127 ; lds off = uniform + l*16B
      async_copy16(A + (size_t)(m0 + r) * K + k0 + sc4, &As[r * 32 + sc4]);
      async_copy16(BT + (size_t)(n0 + r) * K + k0 + sc4, &Bs[r * 32 + sc4]);
    }
    __syncthreads();

    bf16x8 af[4], bf_[4];
    #pragma unroll
    for (int i = 0; i < 4; i++)
      af[i] = *reinterpret_cast<const bf16x8*>(&As[(wm * 64 + i * 16 + l15) * 32 + g * 8]);
    #pragma unroll
    for (int j = 0; j < 4; j++)
      bf_[j] = *reinterpret_cast<const bf16x8*>(&Bs[(wn * 64 + j * 16 + l15) * 32 + g * 8]);
    #pragma unroll
    for (int i = 0; i < 4; i++)
      #pragma unroll
      for (int j = 0; j < 4; j++)
        acc[i][j] = __builtin_amdgcn_mfma_f32_16x16x32_bf16(af[i], bf_[j], acc[i][j], 0, 0, 0);
  }

  #pragma unroll
  for (int i = 0; i < 4; i++) {
    #pragma unroll
    for (int j = 0; j < 4; j++) {
      int mbase = m0 + wm * 64 + i * 16 + g * 4;
      int nn = n0 + wn * 64 + j * 16 + l15;
      float bv = bias[nn];
      #pragma unroll
      for (int rr = 0; rr < 4; rr++) {
        size_t idx = (size_t)(mbase + rr) * N + nn;
        float v = acc[i][j][rr] + bv;
        if (mode == 2) {
          float sig = 1.f / (1.f + expf(-v));
          v = __bfloat162float(addin[idx]) + v * sig;
        }
        Cout[idx] = __float2bfloat16(v);
      }
    }
  }
}

// ---------------- cos/sin table: tab[s*DHH+d] = {cos(rw), sin(rw)} ----------------
__global__ __launch_bounds__(256) void k_sincos(const float* __restrict__ rope_w,
                                                float2* __restrict__ tab) {
  int i = blockIdx.x * 256 + threadIdx.x;
  if (i >= SS * DHH) return;
  float v = rope_w[i];
  tab[i] = make_float2(cosf(v), sinf(v));
}

// ---------------- RoPE in-place on q,k of fused (vectorized, table-driven) ----------------
// ref rotate_half has NO negation: out[d]=x[d]*c[d]+x[d+64]*s[d]; out[d+64]=x[d+64]*c[d+64]+x[d]*s[d+64]
__global__ __launch_bounds__(256) void k_rope(bf16* __restrict__ fused,
                                              const float2* __restrict__ tab) {
  int row = blockIdx.x;
  int s = row & (SS - 1);
  const float2* tr = tab + (size_t)s * DHH;
  int tid = threadIdx.x;
  int isK = tid >> 7, ch = tid & 127;
  int h = ch >> 3, c0 = (ch & 7) * 8;
  const float scale = 0.08838834764831845f;  // 1/sqrt(128); q only
  bf16* base = fused + (size_t)row * NFF + isK * DD + h * DHH;
  bf16x8 lo = *reinterpret_cast<const bf16x8*>(base + c0);
  bf16x8 hi = *reinterpret_cast<const bf16x8*>(base + c0 + 64);
  bf16x8 olo, ohi;
  #pragma unroll
  for (int t = 0; t < 8; t++) {
    int d = c0 + t;
    float2 cl = tr[d], chh = tr[d + 64];
    float x0 = (float)lo[t], x1 = (float)hi[t];
    float r0 = x0 * cl.x + x1 * cl.y;
    float r1 = x1 * chh.x + x0 * chh.y;
    if (!isK) { r0 *= scale; r1 *= scale; }
    olo[t] = (__bf16)r0;
    ohi[t] = (__bf16)r1;
  }
  *reinterpret_cast<bf16x8*>(base + c0) = olo;
  *reinterpret_cast<bf16x8*>(base + c0 + 64) = ohi;
}

// ---------------- causal flash attention, MFMA, 128 q-rows/block ----------------
// grid: (S/128, B*H), 256 threads = 4 waves. Wave w owns q-rows [w*32, w*32+32)
// as 2 strips of 16. K/V staged once per 64-key tile, reused by both strips.
__global__ __launch_bounds__(256) void k_flash(const bf16* __restrict__ fused,
                                               const bf16* __restrict__ vT,
                                               bf16* __restrict__ obuf) {
  __shared__ __align__(16) bf16 smem[24576];  // 48 KiB
  bf16* Ks = smem;          // [4][64][32]   16 KiB (chunk ks over d)
  bf16* Vt = smem + 8192;   // [2][128][32]  16 KiB (chunk kc over keys, row=d)
  bf16* Ps = smem + 16384;  // [2][128][32]  16 KiB (chunk over keys, wave-private rows)
  bf16* Qs = smem;          // staging overlay [4][128][32] = 32 KiB over Ks+Vt

  int qb = blockIdx.x, bh = blockIdx.y;
  int b = bh >> 4, h = bh & 15;
  int tid = threadIdx.x;
  int w = tid >> 6, l = tid & 63;
  int l15 = l & 15, g = l >> 4;

  const bf16* qbase = fused + (size_t)(b * SS + qb * 128) * NFF + h * DHH;
  const bf16* kbase = fused + (size_t)(b * SS) * NFF + DD + h * DHH;
  const bf16* vtb = vT + (size_t)bh * DHH * SS;

  // ---- stage Q (128 rows x 128 d) async ----
  #pragma unroll
  for (int ks = 0; ks < 4; ks++)
    #pragma unroll
    for (int j = 0; j < 2; j++) {
      int row = w * 32 + j * 16 + (l >> 2);
      async_copy16(qbase + (size_t)row * NFF + ks * 32 + (l & 3) * 8,
                   &Qs[ks * 4096 + row * 32 + (l & 3) * 8]);
    }
  __syncthreads();
  bf16x8 qf[2][4];
  #pragma unroll
  for (int p = 0; p < 2; p++)
    #pragma unroll
    for (int ks = 0; ks < 4; ks++)
      qf[p][ks] = *reinterpret_cast<const bf16x8*>(
          &Qs[ks * 4096 + (w * 32 + p * 16 + l15) * 32 + g * 8]);

  f32x4 o[2][8];
  #pragma unroll
  for (int p = 0; p < 2; p++)
    #pragma unroll
    for (int nt = 0; nt < 8; nt++) o[p][nt] = f32x4{0.f, 0.f, 0.f, 0.f};
  float m_i[2][4], l_i[2][4];
  #pragma unroll
  for (int p = 0; p < 2; p++)
    #pragma unroll
    for (int r = 0; r < 4; r++) { m_i[p][r] = -1e30f; l_i[p][r] = 0.f; }
  int qrow0 = qb * 128 + w * 32 + g * 4;  // strip p adds p*16, reg adds r

  int ntiles = 2 * qb + 2;
  for (int kt = 0; kt < ntiles; kt++) {
    __syncthreads();  // all waves done reading Qs/Ks/Vt/Ps region
    #pragma unroll
    for (int ks = 0; ks < 4; ks++)
      async_copy16(kbase + (size_t)(kt * 64 + w * 16 + (l >> 2)) * NFF + ks * 32 + (l & 3) * 8,
                   &Ks[ks * 2048 + w * 512 + l * 8]);
    #pragma unroll
    for (int j = 0; j < 2; j++)
      #pragma unroll
      for (int kc = 0; kc < 2; kc++)
        async_copy16(vtb + (size_t)(j * 64 + w * 16 + (l >> 2)) * SS + kt * 64 + kc * 32 + (l & 3) * 8,
                     &Vt[kc * 4096 + j * 2048 + w * 512 + l * 8]);
    __syncthreads();  // drains vmcnt

    // wave-uniform skip: this wave's rows all < this tile's keys -> fully masked
    if (kt * 64 > qb * 128 + w * 32 + 31) continue;

    // ---- S = Q (2x16 strips x 128) @ K_tile^T ; K-frags shared across strips ----
    f32x4 s[2][4];
    #pragma unroll
    for (int nt = 0; nt < 4; nt++) {
      s[0][nt] = f32x4{0.f, 0.f, 0.f, 0.f};
      s[1][nt] = f32x4{0.f, 0.f, 0.f, 0.f};
      #pragma unroll
      for (int ks = 0; ks < 4; ks++) {
        bf16x8 bfrag = *reinterpret_cast<const bf16x8*>(
            &Ks[ks * 2048 + (nt * 16 + l15) * 32 + g * 8]);
        s[0][nt] = __builtin_amdgcn_mfma_f32_16x16x32_bf16(qf[0][ks], bfrag, s[0][nt], 0, 0, 0);
        s[1][nt] = __builtin_amdgcn_mfma_f32_16x16x32_bf16(qf[1][ks], bfrag, s[1][nt], 0, 0, 0);
      }
    }
    // ---- causal mask + online softmax + Ps write, per strip ----
    float alpha[2][4];
    #pragma unroll
    for (int p = 0; p < 2; p++) {
      #pragma unroll
      for (int nt = 0; nt < 4; nt++) {
        int kk = kt * 64 + nt * 16 + l15;
        #pragma unroll
        for (int r = 0; r < 4; r++)
          if (kk > qrow0 + p * 16 + r) s[p][nt][r] = -1e30f;
      }
      #pragma unroll
      for (int r = 0; r < 4; r++) {
        float mx = fmaxf(fmaxf(s[p][0][r], s[p][1][r]), fmaxf(s[p][2][r], s[p][3][r]));
        mx = fmaxf(mx, __shfl_xor(mx, 1));
        mx = fmaxf(mx, __shfl_xor(mx, 2));
        mx = fmaxf(mx, __shfl_xor(mx, 4));
        mx = fmaxf(mx, __shfl_xor(mx, 8));
        float mnew = fmaxf(m_i[p][r], mx);
        alpha[p][r] = __expf(m_i[p][r] - mnew);
        m_i[p][r] = mnew;
        float ls = 0.f;
        #pragma unroll
        for (int nt = 0; nt < 4; nt++) {
          float pv = __expf(s[p][nt][r] - mnew);
          s[p][nt][r] = pv;
          ls += pv;
        }
        ls += __shfl_xor(ls, 1);
        ls += __shfl_xor(ls, 2);
        ls += __shfl_xor(ls, 4);
        ls += __shfl_xor(ls, 8);
        l_i[p][r] = l_i[p][r] * alpha[p][r] + ls;
      }
      #pragma unroll
      for (int nt = 0; nt < 4; nt++) {
        int kk = nt * 16 + l15;
        #pragma unroll
        for (int r = 0; r < 4; r++)
          *(__bf16*)&Ps[(kk >> 5) * 4096 + (w * 32 + p * 16 + g * 4 + r) * 32 + (kk & 31)] =
              (__bf16)s[p][nt][r];
      }
      #pragma unroll
      for (int nt = 0; nt < 8; nt++)
        #pragma unroll
        for (int r = 0; r < 4; r++) o[p][nt][r] *= alpha[p][r];
    }
    // ---- O += P @ V_tile ; V-frags shared across strips ----
    bf16x8 pf[2][2];
    #pragma unroll
    for (int p = 0; p < 2; p++)
      #pragma unroll
      for (int kc = 0; kc < 2; kc++)
        pf[p][kc] = *reinterpret_cast<const bf16x8*>(
            &Ps[kc * 4096 + (w * 32 + p * 16 + l15) * 32 + g * 8]);
    #pragma unroll
    for (int nt = 0; nt < 8; nt++)
      #pragma unroll
      for (int kc = 0; kc < 2; kc++) {
        bf16x8 bfrag = *reinterpret_cast<const bf16x8*>(
            &Vt[kc * 4096 + (nt * 16 + l15) * 32 + g * 8]);
        o[0][nt] = __builtin_amdgcn_mfma_f32_16x16x32_bf16(pf[0][kc], bfrag, o[0][nt], 0, 0, 0);
        o[1][nt] = __builtin_amdgcn_mfma_f32_16x16x32_bf16(pf[1][kc], bfrag, o[1][nt], 0, 0, 0);
      }
  }

  #pragma unroll
  for (int p = 0; p < 2; p++) {
    float inv[4];
    #pragma unroll
    for (int r = 0; r < 4; r++) inv[r] = 1.f / l_i[p][r];
    #pragma unroll
    for (int nt = 0; nt < 8; nt++)
      #pragma unroll
      for (int r = 0; r < 4; r++) {
        size_t row = (size_t)(b * SS + qrow0 + p * 16 + r);
        obuf[row * DD + h * DHH + nt * 16 + l15] = __float2bfloat16(o[p][nt][r] * inv[r]);
      }
  }
}

// ---------------- LayerNorm(ff) + ReLU -> h (bf16), single-pass, vectorized ----------------
__global__ __launch_bounds__(256) void k_ln1_relu(const bf16* __restrict__ fused,
                                                  const float* __restrict__ gamma,
                                                  const float* __restrict__ beta,
                                                  bf16* __restrict__ h) {
  int row = blockIdx.x;
  const bf16* xr = fused + (size_t)row * NFF + 3 * DD;
  int tid = threadIdx.x;
  bf16x8 v8[4];
  float s = 0.f, ss = 0.f;
  #pragma unroll
  for (int k = 0; k < 4; k++) {
    v8[k] = *reinterpret_cast<const bf16x8*>(xr + (tid + k * 256) * 8);
    #pragma unroll
    for (int t = 0; t < 8; t++) {
      float v = (float)v8[k][t];
      s += v; ss += v * v;
    }
  }
  #pragma unroll
  for (int off = 32; off > 0; off >>= 1) { s += __shfl_down(s, off); ss += __shfl_down(ss, off); }
  __shared__ float red[8];
  int wave = tid >> 6, lane = tid & 63;
  if (lane == 0) { red[wave] = s; red[4 + wave] = ss; }
  __syncthreads();
  if (tid == 0) {
    float S0 = red[0] + red[1] + red[2] + red[3];
    float SQ = red[4] + red[5] + red[6] + red[7];
    float m = S0 / FFF;
    float var = SQ / FFF - m * m;
    red[0] = m;
    red[1] = 1.f / sqrtf(var + LNEPS);
  }
  __syncthreads();
  float m = red[0], inv = red[1];
  bf16* hr = h + (size_t)row * FFF;
  #pragma unroll
  for (int k = 0; k < 4; k++) {
    bf16x8 o8;
    int base = (tid + k * 256) * 8;
    #pragma unroll
    for (int t = 0; t < 8; t++) {
      float v = (float)v8[k][t];
      float y = gamma[base + t] * (v - m) * inv + beta[base + t];
      o8[t] = (__bf16)fmaxf(y, 0.f);
    }
    *reinterpret_cast<bf16x8*>(hr + base) = o8;
  }
}

// ---------------- final LayerNorm (bf16 in -> f32 out), single-pass, vectorized ----------------
__global__ __launch_bounds__(256) void k_ln2(const bf16* __restrict__ yin,
                                             const float* __restrict__ gamma,
                                             const float* __restrict__ beta,
                                             float* __restrict__ out) {
  int row = blockIdx.x;
  const bf16* xr = yin + (size_t)row * DD;
  int tid = threadIdx.x;
  bf16x8 v8 = *reinterpret_cast<const bf16x8*>(xr + tid * 8);
  float s = 0.f, ss = 0.f;
  #pragma unroll
  for (int t = 0; t < 8; t++) {
    float v = (float)v8[t];
    s += v; ss += v * v;
  }
  #pragma unroll
  for (int off = 32; off > 0; off >>= 1) { s += __shfl_down(s, off); ss += __shfl_down(ss, off); }
  __shared__ float red[8];
  int wave = tid >> 6, lane = tid & 63;
  if (lane == 0) { red[wave] = s; red[4 + wave] = ss; }
  __syncthreads();
  if (tid == 0) {
    float S0 = red[0] + red[1] + red[2] + red[3];
    float SQ = red[4] + red[5] + red[6] + red[7];
    float m = S0 / DD;
    float var = SQ / DD - m * m;
    red[0] = m;
    red[1] = 1.f / sqrtf(var + LNEPS);
  }
  __syncthreads();
  float m = red[0], inv = red[1];
  float4* orow = (float4*)(out + (size_t)row * DD);
  #pragma unroll
  for (int k = 0; k < 2; k++) {
    int base = tid * 8 + k * 4;
    float4 r;
    r.x = gamma[base + 0] * ((float)v8[k * 4 + 0] - m) * inv + beta[base + 0];
    r.y = gamma[base + 1] * ((float)v8[k * 4 + 1] - m) * inv + beta[base + 1];
    r.z = gamma[base + 2] * ((float)v8[k * 4 + 2] - m) * inv + beta[base + 2];
    r.w = gamma[base + 3] * ((float)v8[k * 4 + 3] - m) * inv + beta[base + 3];
    orow[tid * 2 + k] = r;
  }
}

extern "C" void kernel_launch(void* const* d_in, const int* in_sizes, int n_in,
                              void* d_out, int out_size, void* d_ws, size_t ws_size,
                              hipStream_t stream) {
  const float* x       = (const float*)d_in[0];
  const float* W_fused = (const float*)d_in[1];
  const float* b_fused = (const float*)d_in[2];
  const float* W_attn  = (const float*)d_in[3];
  const float* b_attn  = (const float*)d_in[4];
  const float* W_ff    = (const float*)d_in[5];
  const float* b_ff    = (const float*)d_in[6];
  const float* gamma1  = (const float*)d_in[7];
  const float* beta1   = (const float*)d_in[8];
  const float* gamma2  = (const float*)d_in[9];
  const float* beta2   = (const float*)d_in[10];
  const float* rope_w  = (const float*)d_in[11];

  char* ws = (char*)d_ws;
  size_t off = 0;
  auto alloc = [&](size_t bytes) -> void* {
    void* p = ws + off;
    off += (bytes + 255) & ~(size_t)255;
    return p;
  };
  bf16* fused = (bf16*)alloc((size_t)MR * NFF * 2);   // 112 MiB
  bf16* xb    = (bf16*)alloc((size_t)MR * DD * 2);    // 16 MiB (dead after fused GEMM)
  bf16* WfT   = (bf16*)alloc((size_t)NFF * DD * 2);   // 56 MiB
  bf16* WaT   = (bf16*)alloc((size_t)DD * DD * 2);    // 8 MiB
  bf16* WffT  = (bf16*)alloc((size_t)DD * FFF * 2);   // 32 MiB
  bf16* hbuf  = (bf16*)alloc((size_t)MR * FFF * 2);   // 64 MiB
  bf16* obuf  = (bf16*)alloc((size_t)MR * DD * 2);    // 16 MiB
  bf16* ybuf  = (bf16*)alloc((size_t)MR * DD * 2);    // 16 MiB
  float* tabf = (float*)alloc((size_t)SS * DHH * 8);  // 2 MiB cos/sin table
  if (off > ws_size) return;
  bf16* vT = xb;               // overlay: V^T [bh][d][s], live vtrans..flash
  float2* tab = (float2*)tabf;

  // 1. convert x -> bf16 ; cos/sin table
  k_convert<<<(MR * DD / 4 + 255) / 256, 256, 0, stream>>>(x, xb, MR * DD / 4);
  k_sincos<<<(SS * DHH + 255) / 256, 256, 0, stream>>>(rope_w, tab);
  // 2. transpose weights -> bf16 B^T
  k_transpose<<<dim3(NFF / 32, DD / 32), dim3(32, 8), 0, stream>>>(W_fused, WfT, DD, NFF);
  k_transpose<<<dim3(DD / 32, DD / 32), dim3(32, 8), 0, stream>>>(W_attn, WaT, DD, DD);
  k_transpose<<<dim3(DD / 32, FFF / 32), dim3(32, 8), 0, stream>>>(W_ff, WffT, FFF, DD);
  // 3. fused = x @ W_fused + b_fused   (bf16 out)
  k_gemm_bt<<<(NFF / 128) * (MR / 128), 256, 0, stream>>>(xb, WfT, b_fused, fused, nullptr,
                                                          MR, NFF, DD, 1);
  // 4. RoPE on q,k (table-driven, vectorized)
  k_rope<<<MR, 256, 0, stream>>>(fused, tab);
  // 5. V^T -> vT (xb now dead), then causal flash attention (MFMA, 128-row q-tiles)
  k_vtrans<<<dim3(SS / 32, DHH / 32, BB * HHN), dim3(32, 8), 0, stream>>>(fused, vT);
  k_flash<<<dim3(SS / 128, BB * HHN), 256, 0, stream>>>(fused, vT, obuf);
  // 6. attn = o @ W_attn + b_attn   (bf16 out -> ybuf)
  k_gemm_bt<<<(DD / 128) * (MR / 128), 256, 0, stream>>>(obuf, WaT, b_attn, ybuf, nullptr,
                                                         MR, DD, DD, 0);
  // 7. h = relu(layernorm(ff))   (bf16)
  k_ln1_relu<<<MR, 256, 0, stream>>>(fused, gamma1, beta1, hbuf);
  // 8. ybuf = attn + silu(h @ W_ff + b_ff)   (in-place add, bf16)
  k_gemm_bt<<<(DD / 128) * (MR / 128), 256, 0, stream>>>(hbuf, WffT, b_ff, ybuf, ybuf,
                                                         MR, DD, FFF, 2);
  // 9. out = layernorm(ybuf)
  k_ln2<<<MR, 256, 0, stream>>>(ybuf, gamma2, beta2, (float*)d_out);
}